// Round 5
// baseline (744.054 us; speedup 1.0000x reference)
//
#include <hip/hip_runtime.h>
#include <hip/hip_bf16.h>
#include <cstdint>
#include <cstddef>

typedef __hip_bfloat16 bf16;
typedef __bf16 bf16x8 __attribute__((ext_vector_type(8)));
typedef float f32x4 __attribute__((ext_vector_type(4)));

#define DEVFN static __device__ __forceinline__

// async global->LDS, 16B per lane. LDS dest must be wave-uniform base + lane*16.
DEVFN void async16(const void* g, void* l) {
  __builtin_amdgcn_global_load_lds(
      (const __attribute__((address_space(1))) uint32_t*)g,
      (__attribute__((address_space(3))) uint32_t*)l, 16, 0, 0);
}

DEVFN float eluf(float v) { return v > 0.f ? v : expm1f(v); }
DEVFN float softplusf(float x) {
  return x > 0.f ? x + log1pf(expf(-x)) : log1pf(expf(x));
}

// non-temporal bf16 store: C-outputs must NOT evict the L2-resident A/B tiles
DEVFN void nt_store_bf16(float v, bf16* p) {
  bf16 h = __float2bfloat16(v);
  unsigned short u;
  __builtin_memcpy(&u, &h, 2);
  __builtin_nontemporal_store(u, (unsigned short*)p);
}

// ---------------------------------------------------------------------------
// BK=64 XOR-swizzled K-loop. A tile 128x64, B tile (NCHB*32)x64.
// LDS slot (row, g) holds global (row, g ^ (row&7)); staging applies the
// swizzle on the GLOBAL address (LDS dest is pinned to lane*16), fragment
// reads apply it on the LDS side -> ds_read_b128 banks are 2-way (free).
template <int NCHB, int NFB>
DEVFN void kloop64(const bf16* (&gA)[4], const bf16* (&gB)[NCHB], bf16* As,
                   bf16* Bs, int tid, const bf16* aBase, const bf16* bBase,
                   const int (&colsel)[2], f32x4 (&acc)[4][NFB], int kiters) {
  for (int kt = 0; kt < kiters; ++kt) {
#pragma unroll
    for (int c = 0; c < 4; ++c) async16(gA[c], As + c * 2048 + tid * 8);
#pragma unroll
    for (int c = 0; c < NCHB; ++c) async16(gB[c], Bs + c * 2048 + tid * 8);
#pragma unroll
    for (int c = 0; c < 4; ++c) gA[c] += 64;
#pragma unroll
    for (int c = 0; c < NCHB; ++c) gB[c] += 64;
    __syncthreads();
#pragma unroll
    for (int s = 0; s < 2; ++s) {
      bf16x8 af[4], bfv[NFB];
#pragma unroll
      for (int r = 0; r < 4; ++r)
        af[r] = *(const bf16x8*)(aBase + r * 1024 + colsel[s]);
#pragma unroll
      for (int c = 0; c < NFB; ++c)
        bfv[c] = *(const bf16x8*)(bBase + c * 1024 + colsel[s]);
#pragma unroll
      for (int r = 0; r < 4; ++r)
#pragma unroll
        for (int c = 0; c < NFB; ++c)
          acc[r][c] = __builtin_amdgcn_mfma_f32_16x16x32_bf16(af[r], bfv[c], acc[r][c], 0, 0, 0);
    }
    __syncthreads();
  }
}

// ---------------------------------------------------------------------------
// prep: all transposes/converts/bias-concat/bucket-bookkeeping in ONE launch
DEVFN void transpose_tile(const float* src, bf16* dst, int R, int C, int bx, int by) {
  __shared__ float tile[32][33];
  const int c0 = bx * 32, r0 = by * 32;
  const int tx = threadIdx.x & 31, ty = threadIdx.x >> 5;
#pragma unroll
  for (int rr = ty; rr < 32; rr += 8)
    tile[rr][tx] = src[(size_t)(r0 + rr) * C + c0 + tx];
  __syncthreads();
#pragma unroll
  for (int rr = ty; rr < 32; rr += 8)
    dst[(size_t)(c0 + rr) * R + r0 + tx] = __float2bfloat16(tile[tx][rr]);
}

__global__ __launch_bounds__(256) void prep_all_k(
    const float* __restrict__ x, bf16* __restrict__ xb,
    const float* __restrict__ yw0, const float* __restrict__ dw0,
    const float* __restrict__ zw0, const float* __restrict__ tw0,
    bf16* __restrict__ BtL1,
    const float* __restrict__ yw1, const float* __restrict__ dw1,
    const float* __restrict__ zw1, bf16* __restrict__ BtL2,
    const float* __restrict__ tw1, bf16* __restrict__ tw1t,
    const float* __restrict__ zhW, bf16* __restrict__ zhWt,
    const float* __restrict__ yb0, const float* __restrict__ db0,
    const float* __restrict__ zb0, const float* __restrict__ tb0,
    const float* __restrict__ yb1, const float* __restrict__ db1,
    const float* __restrict__ zb1,
    float* __restrict__ biasAll, float* __restrict__ r0All,
    float* __restrict__ r1All, float* __restrict__ biasL2,
    const int* __restrict__ t, int* __restrict__ cnt, int* __restrict__ seg,
    int* __restrict__ rank, int* __restrict__ sids) {
  int l = blockIdx.x;
  if (l < 8192) {  // x fp32 -> bf16, 8 elems/thread
    size_t i = ((size_t)l * 256 + threadIdx.x) * 8;
    float4 v0 = *(const float4*)(x + i);
    float4 v1 = *(const float4*)(x + i + 4);
    union { bf16 h[8]; uint4 u; } o;
    o.h[0] = __float2bfloat16(v0.x); o.h[1] = __float2bfloat16(v0.y);
    o.h[2] = __float2bfloat16(v0.z); o.h[3] = __float2bfloat16(v0.w);
    o.h[4] = __float2bfloat16(v1.x); o.h[5] = __float2bfloat16(v1.y);
    o.h[6] = __float2bfloat16(v1.z); o.h[7] = __float2bfloat16(v1.w);
    *(uint4*)(xb + i) = o.u;
    return;
  }
  l -= 8192;
  if (l < 4096) {  // BtL1: {yw0,dw0,zw0[2:],tw0} transposed
    int z = l >> 10, rem = l & 1023, bx = rem & 31, by = rem >> 5;
    const float* src = (z == 0) ? yw0 : (z == 1) ? dw0 : (z == 2) ? zw0 + 2048 : tw0;
    int C = (z == 3) ? 256 : 1024;
    if (bx * 32 < C)
      transpose_tile(src, BtL1 + (size_t)z * 1024 * 1024, 1024, C, bx, by);
    return;
  }
  l -= 4096;
  if (l < 3072) {  // BtL2: {yw1,dw1,zw1} transposed
    int z = l >> 10, rem = l & 1023, bx = rem & 31, by = rem >> 5;
    const float* src = (z == 0) ? yw1 : (z == 1) ? dw1 : zw1;
    transpose_tile(src, BtL2 + (size_t)z * 1024 * 1024, 1024, 1024, bx, by);
    return;
  }
  l -= 3072;
  if (l < 64) {  // tw1t
    transpose_tile(tw1, tw1t, 256, 256, l & 7, l >> 3);
    return;
  }
  l -= 64;
  if (l < 3584) {  // zhWt: 7 x [1024][512] -> [512][1024]
    int z = l >> 9, rem = l & 511, bx = rem & 15, by = rem >> 4;
    transpose_tile(zhW + (size_t)z * 1024 * 512, zhWt + (size_t)z * 512 * 1024,
                   1024, 512, bx, by);
    return;
  }
  l -= 3584;
  if (l < 13) {  // bias / rank-2 concat
    int i = l * 256 + threadIdx.x;
    if (i >= 3328) return;
    float b;
    if (i < 1024) b = yb0[i];
    else if (i < 2048) b = db0[i - 1024];
    else if (i < 3072) b = zb0[i - 2048];
    else b = tb0[i - 3072];
    biasAll[i] = b;
    bool inz = (i >= 2048 && i < 3072);
    r0All[i] = inz ? zw0[i - 2048] : 0.f;
    r1All[i] = inz ? zw0[1024 + (i - 2048)] : 0.f;
    if (i < 3072)
      biasL2[i] = (i < 1024) ? yb1[i] : (i < 2048) ? db1[i - 1024] : zb1[i - 2048];
    return;
  }
  {  // bucket bookkeeping: single block, 256 threads x 64 items
    __shared__ int h[8], sseg[8];
    const int tid = threadIdx.x;
    if (tid < 8) h[tid] = 0;
    __syncthreads();
    const int base = tid * 64;
    int lc[7] = {0, 0, 0, 0, 0, 0, 0};
    for (int i = 0; i < 64; ++i) lc[t[base + i]]++;
    int myoff[7];
#pragma unroll
    for (int k = 0; k < 7; ++k) myoff[k] = atomicAdd(&h[k], lc[k]);
    __syncthreads();
    if (tid == 0) {
      int s = 0;
      for (int k = 0; k < 7; ++k) { sseg[k] = s; s += h[k]; }
      sseg[7] = s;
    }
    __syncthreads();
    if (tid < 7) { cnt[tid] = h[tid]; seg[tid] = sseg[tid]; }
    if (tid == 7) seg[7] = sseg[7];
    int cur[7];
#pragma unroll
    for (int k = 0; k < 7; ++k) cur[k] = sseg[k] + myoff[k];
    for (int i = 0; i < 64; ++i) {
      int b = base + i, k = t[b];
      int r = cur[k]++;
      rank[b] = r;
      sids[r] = b;
    }
  }
}

// ---------------------------------------------------------------------------
// fused layer-1: [16384,1024] x [1024,3328] -> {a1y,a1d,a1z,ht1}
// XCD-swizzled 1D grid; BK=64 swizzled k-loop; NT epilogue stores.
__global__ __launch_bounds__(256) void gemm_l1_k(
    const bf16* __restrict__ A, const bf16* __restrict__ Bt,
    const float* __restrict__ biasAll, const float* __restrict__ r0All,
    const float* __restrict__ r1All, const float* __restrict__ yv,
    const float* __restrict__ dv, bf16* __restrict__ a1y,
    bf16* __restrict__ a1d, bf16* __restrict__ a1z, bf16* __restrict__ ht1) {
  __shared__ bf16 As[128 * 64];
  __shared__ bf16 Bs[128 * 64];
  const int tid = threadIdx.x, lane = tid & 63, wid = tid >> 6;
  const int wm = wid >> 1, wn = wid & 1, quad = lane >> 4, l15 = lane & 15;
  const int id = blockIdx.x;
  const int xcd = id & 7, lid = id >> 3;               // lid in [0,416)
  const int pass = lid / 208, rem = lid - pass * 208;  // 208 = 8m x 26n
  const int mt = xcd * 16 + pass * 8 + (rem & 7), nt = rem >> 3;
  const int bm0 = mt * 128, bn0 = nt * 128;
  const int sr3 = tid >> 3, scol = ((tid & 7) ^ (sr3 & 7)) * 8;
  const bf16* gA[4];
  const bf16* gB[4];
#pragma unroll
  for (int c = 0; c < 4; ++c) {
    gA[c] = A + (size_t)(bm0 + c * 32 + sr3) * 1024 + scol;
    gB[c] = Bt + (size_t)(bn0 + c * 32 + sr3) * 1024 + scol;
  }
  const bf16* aBase = &As[(wm * 64 + l15) * 64];
  const bf16* bBase = &Bs[(wn * 64 + l15) * 64];
  int colsel[2];
#pragma unroll
  for (int s = 0; s < 2; ++s) colsel[s] = ((s * 4 + quad) ^ (l15 & 7)) * 8;
  f32x4 acc[4][4] = {};
  kloop64<4, 4>(gA, gB, As, Bs, tid, aBase, bBase, colsel, acc, 16);

  const int g = nt >> 3;
  bf16* dst = (g == 0) ? a1y : (g == 1) ? a1d : (g == 2) ? a1z : ht1;
  const int ldc = (g == 3) ? 256 : 1024;
  const int colb = bn0 - g * 1024;
  float bv[4], z0[4], z1[4];
#pragma unroll
  for (int c = 0; c < 4; ++c) {
    int gn = bn0 + wn * 64 + c * 16 + l15;
    bv[c] = biasAll[gn]; z0[c] = r0All[gn]; z1[c] = r1All[gn];
  }
#pragma unroll
  for (int r = 0; r < 4; ++r) {
#pragma unroll
    for (int q = 0; q < 4; ++q) {
      int gm = bm0 + wm * 64 + r * 16 + quad * 4 + q;
      float yy = yv[gm], dd = dv[gm];
#pragma unroll
      for (int c = 0; c < 4; ++c) {
        float v = acc[r][c][q] + bv[c] + yy * z0[c] + dd * z1[c];
        nt_store_bf16(eluf(v), dst + (size_t)gm * ldc + colb + wn * 64 + c * 16 + l15);
      }
    }
  }
}

// fused layer-2 + t-layer-2: blocks [0,3072) = y1|d1|z1 (K=1024, XCD-swizzled),
// blocks [3072,3328) = t1 (K=256). hz rows written permuted via rank[].
__global__ __launch_bounds__(256) void gemm_l2t_k(
    const bf16* __restrict__ a1y, const bf16* __restrict__ a1d,
    const bf16* __restrict__ a1z, const bf16* __restrict__ ht1,
    const bf16* __restrict__ BtL2, const bf16* __restrict__ tw1t,
    const float* __restrict__ biasL2, const float* __restrict__ tb1,
    bf16* __restrict__ hyd, bf16* __restrict__ hzg, bf16* __restrict__ ht2,
    const int* __restrict__ rank) {
  __shared__ bf16 As[128 * 64];
  __shared__ bf16 Bs[128 * 64];
  const int tid = threadIdx.x, lane = tid & 63, wid = tid >> 6;
  const int wm = wid >> 1, wn = wid & 1, quad = lane >> 4, l15 = lane & 15;
  const int id = blockIdx.x;
  int bm0, bn0, Ka, g;
  const bf16 *Aptr, *Bptr;
  if (id < 3072) {
    const int xcd = id & 7, lid = id >> 3;               // lid in [0,384)
    const int pass = lid / 192, rem = lid - pass * 192;  // 192 = 8m x 24n
    const int mt = xcd * 16 + pass * 8 + (rem & 7), nt = rem >> 3;
    bm0 = mt * 128; bn0 = nt * 128; Ka = 1024;
    g = nt >> 3;
    Aptr = (g == 0) ? a1y : (g == 1) ? a1d : a1z;
    Bptr = BtL2;
  } else {
    const int local = id - 3072;
    bm0 = (local >> 1) * 128; bn0 = (local & 1) * 128; Ka = 256;
    g = 3; Aptr = ht1; Bptr = tw1t;
  }
  const int sr3 = tid >> 3, scol = ((tid & 7) ^ (sr3 & 7)) * 8;
  const bf16* gA[4];
  const bf16* gB[4];
#pragma unroll
  for (int c = 0; c < 4; ++c) {
    gA[c] = Aptr + (size_t)(bm0 + c * 32 + sr3) * Ka + scol;
    gB[c] = Bptr + (size_t)(bn0 + c * 32 + sr3) * Ka + scol;
  }
  const bf16* aBase = &As[(wm * 64 + l15) * 64];
  const bf16* bBase = &Bs[(wn * 64 + l15) * 64];
  int colsel[2];
#pragma unroll
  for (int s = 0; s < 2; ++s) colsel[s] = ((s * 4 + quad) ^ (l15 & 7)) * 8;
  f32x4 acc[4][4] = {};
  kloop64<4, 4>(gA, gB, As, Bs, tid, aBase, bBase, colsel, acc, Ka >> 6);

  const float* bias = (g == 3) ? tb1 : biasL2;
  float bv[4];
#pragma unroll
  for (int c = 0; c < 4; ++c) bv[c] = bias[bn0 + wn * 64 + c * 16 + l15];
#pragma unroll
  for (int r = 0; r < 4; ++r) {
#pragma unroll
    for (int q = 0; q < 4; ++q) {
      int gm = bm0 + wm * 64 + r * 16 + quad * 4 + q;
      bf16* dst; size_t rowoff;
      if (g == 2) { dst = hzg; rowoff = (size_t)rank[gm] * 1024 + (size_t)(bn0 - 2048); }
      else if (g == 3) { dst = ht2; rowoff = (size_t)gm * 256 + bn0; }
      else { dst = hyd; rowoff = (size_t)gm * 2048 + bn0; }
#pragma unroll
      for (int c = 0; c < 4; ++c) {
        float v = acc[r][c][q] + bv[c];
        nt_store_bf16(eluf(v), dst + rowoff + wn * 64 + c * 16 + l15);
      }
    }
  }
}

// ---------------------------------------------------------------------------
// merged tail: z-head bucketed GEMM (blocks < ZB) + y/d heads + t-logits.
// zhead: per-bucket [cnt x 1024] x [1024 x 512], 128x64 tiles, BK=64 swizzle.
#define ZMT 28  // max m-tiles per bucket (covers 3584 rows; mean 2341, +27 sigma)
#define ZB (7 * ZMT * 8)
__global__ __launch_bounds__(256) void tail_k(
    const bf16* __restrict__ hzg, const bf16* __restrict__ zhWt,
    const float* __restrict__ zhb, const int* __restrict__ seg,
    const int* __restrict__ cnts, const int* __restrict__ sids,
    const bf16* __restrict__ hyd, const bf16* __restrict__ ht2,
    const int* __restrict__ t, const float* __restrict__ yhW,
    const float* __restrict__ yhb, const float* __restrict__ dhW,
    const float* __restrict__ dhb, const float* __restrict__ tw2,
    const float* __restrict__ tb2, float* __restrict__ out) {
  __shared__ bf16 As[128 * 64];  // 16 KB
  __shared__ bf16 Bs[64 * 64];   // 8 KB
  const int tid = threadIdx.x, lane = tid & 63, wid = tid >> 6;
  const int wv = wid, quad = lane >> 4, l15 = lane & 15;
  if (blockIdx.x < ZB) {
    const int kb = blockIdx.x / (ZMT * 8);
    const int r = blockIdx.x % (ZMT * 8);
    const int cnt = cnts[kb];
    const int bm0 = (r >> 3) * 128;
    if (bm0 >= cnt) return;
    const int n0 = (r & 7) * 64;
    const int wm = wid >> 1, wn = wid & 1;
    const int base = seg[kb];
    const int sr3 = tid >> 3, scol = ((tid & 7) ^ (sr3 & 7)) * 8;
    const bf16* gA[4];
    const bf16* gB[2];
#pragma unroll
    for (int c = 0; c < 4; ++c) {
      int rr = bm0 + c * 32 + sr3;
      if (rr >= cnt) rr = cnt - 1;
      gA[c] = hzg + (size_t)(base + rr) * 1024 + scol;
    }
#pragma unroll
    for (int c = 0; c < 2; ++c)
      gB[c] = zhWt + (size_t)kb * 512 * 1024 + (size_t)(n0 + c * 32 + sr3) * 1024 + scol;
    const bf16* aBase = &As[(wm * 64 + l15) * 64];
    const bf16* bBase = &Bs[(wn * 32 + l15) * 64];
    int colsel[2];
#pragma unroll
    for (int s = 0; s < 2; ++s) colsel[s] = ((s * 4 + quad) ^ (l15 & 7)) * 8;
    f32x4 acc[4][2] = {};
    kloop64<2, 2>(gA, gB, As, Bs, tid, aBase, bBase, colsel, acc, 16);
    const float* bias = zhb + (size_t)kb * 512;
    float bv[2]; int gnn[2];
#pragma unroll
    for (int c = 0; c < 2; ++c) {
      gnn[c] = n0 + wn * 32 + c * 16 + l15;
      bv[c] = bias[gnn[c]];
    }
#pragma unroll
    for (int r2 = 0; r2 < 4; ++r2)
#pragma unroll
      for (int q = 0; q < 4; ++q) {
        int lm = bm0 + wm * 64 + r2 * 16 + quad * 4 + q;
        if (lm < cnt) {
          int gm = sids[base + lm];
          size_t ob = (size_t)gm * 523 + 11;
#pragma unroll
          for (int c = 0; c < 2; ++c) {
            float v = acc[r2][c][q] + bv[c];
            int n = gnn[c];
            float o = (n < 256) ? fminf(fmaxf(v, -100.f), 100.f)
                                : fminf(softplusf(v) + 0.001f, 100.f);
            __builtin_nontemporal_store(o, out + ob + n);
          }
        }
      }
    return;
  }
  const int hid = blockIdx.x - ZB;
  if (hid < 4096) {  // y/d heads
    const int b = hid * 4 + wv;
    const int tb = t[b];
    const float* yW = yhW + (size_t)tb * 2048;
    const float* dW = dhW + (size_t)tb * 2048;
    float s0 = 0.f, s1 = 0.f, s2 = 0.f, s3 = 0.f;
    for (int i = lane; i < 1024; i += 64) {
      float a = __bfloat162float(hyd[(size_t)b * 2048 + i]);
      float c = __bfloat162float(hyd[(size_t)b * 2048 + 1024 + i]);
      s0 += a * yW[2 * i]; s1 += a * yW[2 * i + 1];
      s2 += c * dW[2 * i]; s3 += c * dW[2 * i + 1];
    }
#pragma unroll
    for (int off = 32; off > 0; off >>= 1) {
      s0 += __shfl_down(s0, off); s1 += __shfl_down(s1, off);
      s2 += __shfl_down(s2, off); s3 += __shfl_down(s3, off);
    }
    if (lane == 0) {
      size_t o = (size_t)b * 523;
      __builtin_nontemporal_store(fminf(fmaxf(s0 + yhb[tb * 2], -1e6f), 1e6f), out + o + 7);
      __builtin_nontemporal_store(fminf(softplusf(s1 + yhb[tb * 2 + 1]) + 1e-3f, 1e6f), out + o + 8);
      __builtin_nontemporal_store(fminf(fmaxf(s2 + dhb[tb * 2], -1e6f), 1e6f), out + o + 9);
      __builtin_nontemporal_store(fminf(softplusf(s3 + dhb[tb * 2 + 1]) + 1e-3f, 1e6f), out + o + 10);
    }
  } else {  // t logits
    const int b = (hid - 4096) * 4 + wv;
    float h[4];
#pragma unroll
    for (int j = 0; j < 4; ++j)
      h[j] = __bfloat162float(ht2[(size_t)b * 256 + lane * 4 + j]);
    float pp[7];
#pragma unroll
    for (int kk = 0; kk < 7; ++kk) {
      float s = 0.f;
#pragma unroll
      for (int j = 0; j < 4; ++j) s += h[j] * tw2[(lane * 4 + j) * 7 + kk];
      pp[kk] = s;
    }
#pragma unroll
    for (int kk = 0; kk < 7; ++kk)
#pragma unroll
      for (int off = 32; off > 0; off >>= 1) pp[kk] += __shfl_down(pp[kk], off);
    if (lane == 0) {
#pragma unroll
      for (int kk = 0; kk < 7; ++kk) {
        float v = eluf(pp[kk] + tb2[kk]);
        __builtin_nontemporal_store(fminf(fmaxf(v, -10.f), 10.f), out + (size_t)b * 523 + kk);
      }
    }
  }
}

// ---------------------------------------------------------------------------
extern "C" void kernel_launch(void* const* d_in, const int* in_sizes, int n_in,
                              void* d_out, int out_size, void* d_ws, size_t ws_size,
                              hipStream_t stream) {
  const float* x   = (const float*)d_in[0];
  const int*   t   = (const int*)d_in[1];
  const float* yv  = (const float*)d_in[2];
  const float* dv  = (const float*)d_in[3];
  const float* tw0 = (const float*)d_in[4];
  const float* tb0 = (const float*)d_in[5];
  const float* tw1 = (const float*)d_in[6];
  const float* tb1 = (const float*)d_in[7];
  const float* tw2 = (const float*)d_in[8];
  const float* tb2 = (const float*)d_in[9];
  const float* yw0 = (const float*)d_in[10];
  const float* yb0 = (const float*)d_in[11];
  const float* yw1 = (const float*)d_in[12];
  const float* yb1 = (const float*)d_in[13];
  const float* yhW = (const float*)d_in[14];
  const float* yhb = (const float*)d_in[15];
  const float* dw0 = (const float*)d_in[16];
  const float* db0 = (const float*)d_in[17];
  const float* dw1 = (const float*)d_in[18];
  const float* db1 = (const float*)d_in[19];
  const float* dhW = (const float*)d_in[20];
  const float* dhb = (const float*)d_in[21];
  const float* zw0 = (const float*)d_in[22];
  const float* zb0 = (const float*)d_in[23];
  const float* zw1 = (const float*)d_in[24];
  const float* zb1 = (const float*)d_in[25];
  const float* zhW = (const float*)d_in[26];
  const float* zhb = (const float*)d_in[27];
  float* out = (float*)d_out;

  const int B = 16384;
  char* p = (char*)d_ws;
  auto take = [&](size_t bytes) {
    char* r = p;
    p += (bytes + 255) & ~(size_t)255;
    return r;
  };
  bf16*  BtL1    = (bf16*)take((size_t)3328 * 1024 * 2);
  bf16*  BtL2    = (bf16*)take((size_t)3072 * 1024 * 2);
  bf16*  tw1t    = (bf16*)take((size_t)256 * 256 * 2);
  bf16*  zhWt    = (bf16*)take((size_t)7 * 512 * 1024 * 2);
  float* biasAll = (float*)take(3328 * 4);
  float* r0All   = (float*)take(3328 * 4);
  float* r1All   = (float*)take(3328 * 4);
  float* biasL2  = (float*)take(3072 * 4);
  int*   cnt     = (int*)take(8 * 4);
  int*   seg     = (int*)take(8 * 4);
  int*   rank    = (int*)take((size_t)B * 4);
  int*   sids    = (int*)take((size_t)B * 4);
  bf16*  xb      = (bf16*)take((size_t)B * 1024 * 2);  // reused as hzg after L1
  bf16*  a1y     = (bf16*)take((size_t)B * 1024 * 2);
  bf16*  a1d     = (bf16*)take((size_t)B * 1024 * 2);
  bf16*  a1z     = (bf16*)take((size_t)B * 1024 * 2);
  bf16*  ht1     = (bf16*)take((size_t)B * 256 * 2);
  bf16*  hyd     = (bf16*)take((size_t)B * 2048 * 2);
  bf16*  ht2     = (bf16*)take((size_t)B * 256 * 2);
  bf16*  hzg     = xb;

  prep_all_k<<<19022, 256, 0, stream>>>(x, xb, yw0, dw0, zw0, tw0, BtL1,
                                        yw1, dw1, zw1, BtL2, tw1, tw1t, zhW, zhWt,
                                        yb0, db0, zb0, tb0, yb1, db1, zb1,
                                        biasAll, r0All, r1All, biasL2,
                                        t, cnt, seg, rank, sids);
  gemm_l1_k<<<3328, 256, 0, stream>>>(xb, BtL1, biasAll, r0All, r1All,
                                      yv, dv, a1y, a1d, a1z, ht1);
  gemm_l2t_k<<<3328, 256, 0, stream>>>(a1y, a1d, a1z, ht1, BtL2, tw1t,
                                       biasL2, tb1, hyd, hzg, ht2, rank);
  tail_k<<<ZB + 8192, 256, 0, stream>>>(hzg, zhWt, zhb, seg, cnt, sids,
                                        hyd, ht2, t, yhW, yhb, dhW, dhb,
                                        tw2, tb2, out);
}

// Round 6
// 661.787 us; speedup vs baseline: 1.1243x; 1.1243x over previous
//
#include <hip/hip_runtime.h>
#include <hip/hip_bf16.h>
#include <cstdint>
#include <cstddef>

typedef __hip_bfloat16 bf16;
typedef __bf16 bf16x8 __attribute__((ext_vector_type(8)));
typedef float f32x4 __attribute__((ext_vector_type(4)));

#define DEVFN static __device__ __forceinline__

// async global->LDS, 16B per lane. LDS dest must be wave-uniform base + lane*16.
DEVFN void async16(const void* g, void* l) {
  __builtin_amdgcn_global_load_lds(
      (const __attribute__((address_space(1))) uint32_t*)g,
      (__attribute__((address_space(3))) uint32_t*)l, 16, 0, 0);
}

DEVFN float eluf(float v) { return v > 0.f ? v : expm1f(v); }
DEVFN float softplusf(float x) {
  return x > 0.f ? x + log1pf(expf(-x)) : log1pf(expf(x));
}

// ---------------------------------------------------------------------------
// BK=32 swizzled K-loop. Row = 32 bf16 = 4 chunks of 16B. LDS slot (row,chunk)
// holds global (row, chunk ^ ((row>>1)&3)): staging XORs the GLOBAL column
// (LDS dest pinned to lane*16); fragment reads XOR on the LDS side. Quad-read
// banks = (l15&1)*16 + ((l15>>1)&3 ^ quad)*4 -> 8 groups x 2 lanes = conflict-
// free. Key is invariant over r-frags (r*16>>1 === 0 mod 4).
template <int NAH, int NBH, int NFB>
DEVFN void kloop32(const bf16* (&gA)[NAH], const bf16* (&gB)[NBH], bf16* As,
                   bf16* Bs, int tid, const bf16* aBase, const bf16* bBase,
                   int colsel, f32x4 (&acc)[4][NFB], int kiters) {
  for (int kt = 0; kt < kiters; ++kt) {
#pragma unroll
    for (int c = 0; c < NAH; ++c) async16(gA[c], As + c * 2048 + tid * 8);
#pragma unroll
    for (int c = 0; c < NBH; ++c) async16(gB[c], Bs + c * 2048 + tid * 8);
#pragma unroll
    for (int c = 0; c < NAH; ++c) gA[c] += 32;
#pragma unroll
    for (int c = 0; c < NBH; ++c) gB[c] += 32;
    __syncthreads();
    bf16x8 af[4], bfv[NFB];
#pragma unroll
    for (int r = 0; r < 4; ++r) af[r] = *(const bf16x8*)(aBase + r * 512 + colsel);
#pragma unroll
    for (int c = 0; c < NFB; ++c) bfv[c] = *(const bf16x8*)(bBase + c * 512 + colsel);
#pragma unroll
    for (int r = 0; r < 4; ++r)
#pragma unroll
      for (int c = 0; c < NFB; ++c)
        acc[r][c] = __builtin_amdgcn_mfma_f32_16x16x32_bf16(af[r], bfv[c], acc[r][c], 0, 0, 0);
    __syncthreads();
  }
}

// staging column offset (bf16 elems) for thread tid: chunk (tid&3) of row
// (tid>>2) must hold global chunk (tid&3)^((row>>1)&3) = (tid&3)^((tid>>3)&3)
DEVFN int swz_scol(int tid) { return (((tid & 3) ^ ((tid >> 3) & 3)) * 8); }
// fragment column select for lane: global chunk `quad` of row l15 lives in LDS
// chunk quad^((l15>>1)&3)
DEVFN int swz_colsel(int quad, int l15) { return ((quad ^ ((l15 >> 1) & 3)) * 8); }

// ---------------------------------------------------------------------------
// prep: all transposes/converts/bias-concat/bucket-bookkeeping in ONE launch
DEVFN void transpose_tile(const float* src, bf16* dst, int R, int C, int bx, int by) {
  __shared__ float tile[32][33];
  const int c0 = bx * 32, r0 = by * 32;
  const int tx = threadIdx.x & 31, ty = threadIdx.x >> 5;
#pragma unroll
  for (int rr = ty; rr < 32; rr += 8)
    tile[rr][tx] = src[(size_t)(r0 + rr) * C + c0 + tx];
  __syncthreads();
#pragma unroll
  for (int rr = ty; rr < 32; rr += 8)
    dst[(size_t)(c0 + rr) * R + r0 + tx] = __float2bfloat16(tile[tx][rr]);
}

__global__ __launch_bounds__(256) void prep_all_k(
    const float* __restrict__ x, bf16* __restrict__ xb,
    const float* __restrict__ yw0, const float* __restrict__ dw0,
    const float* __restrict__ zw0, const float* __restrict__ tw0,
    bf16* __restrict__ BtL1,
    const float* __restrict__ yw1, const float* __restrict__ dw1,
    const float* __restrict__ zw1, bf16* __restrict__ BtL2,
    const float* __restrict__ tw1, bf16* __restrict__ tw1t,
    const float* __restrict__ zhW, bf16* __restrict__ zhWt,
    const float* __restrict__ yb0, const float* __restrict__ db0,
    const float* __restrict__ zb0, const float* __restrict__ tb0,
    const float* __restrict__ yb1, const float* __restrict__ db1,
    const float* __restrict__ zb1,
    float* __restrict__ biasAll, float* __restrict__ r0All,
    float* __restrict__ r1All, float* __restrict__ biasL2,
    const int* __restrict__ t, int* __restrict__ cnt, int* __restrict__ seg,
    int* __restrict__ rank, int* __restrict__ sids) {
  int l = blockIdx.x;
  if (l < 8192) {  // x fp32 -> bf16, 8 elems/thread
    size_t i = ((size_t)l * 256 + threadIdx.x) * 8;
    float4 v0 = *(const float4*)(x + i);
    float4 v1 = *(const float4*)(x + i + 4);
    union { bf16 h[8]; uint4 u; } o;
    o.h[0] = __float2bfloat16(v0.x); o.h[1] = __float2bfloat16(v0.y);
    o.h[2] = __float2bfloat16(v0.z); o.h[3] = __float2bfloat16(v0.w);
    o.h[4] = __float2bfloat16(v1.x); o.h[5] = __float2bfloat16(v1.y);
    o.h[6] = __float2bfloat16(v1.z); o.h[7] = __float2bfloat16(v1.w);
    *(uint4*)(xb + i) = o.u;
    return;
  }
  l -= 8192;
  if (l < 4096) {  // BtL1: {yw0,dw0,zw0[2:],tw0} transposed
    int z = l >> 10, rem = l & 1023, bx = rem & 31, by = rem >> 5;
    const float* src = (z == 0) ? yw0 : (z == 1) ? dw0 : (z == 2) ? zw0 + 2048 : tw0;
    int C = (z == 3) ? 256 : 1024;
    if (bx * 32 < C)
      transpose_tile(src, BtL1 + (size_t)z * 1024 * 1024, 1024, C, bx, by);
    return;
  }
  l -= 4096;
  if (l < 3072) {  // BtL2: {yw1,dw1,zw1} transposed
    int z = l >> 10, rem = l & 1023, bx = rem & 31, by = rem >> 5;
    const float* src = (z == 0) ? yw1 : (z == 1) ? dw1 : zw1;
    transpose_tile(src, BtL2 + (size_t)z * 1024 * 1024, 1024, 1024, bx, by);
    return;
  }
  l -= 3072;
  if (l < 64) {  // tw1t
    transpose_tile(tw1, tw1t, 256, 256, l & 7, l >> 3);
    return;
  }
  l -= 64;
  if (l < 3584) {  // zhWt: 7 x [1024][512] -> [512][1024]
    int z = l >> 9, rem = l & 511, bx = rem & 15, by = rem >> 4;
    transpose_tile(zhW + (size_t)z * 1024 * 512, zhWt + (size_t)z * 512 * 1024,
                   1024, 512, bx, by);
    return;
  }
  l -= 3584;
  if (l < 13) {  // bias / rank-2 concat
    int i = l * 256 + threadIdx.x;
    if (i >= 3328) return;
    float b;
    if (i < 1024) b = yb0[i];
    else if (i < 2048) b = db0[i - 1024];
    else if (i < 3072) b = zb0[i - 2048];
    else b = tb0[i - 3072];
    biasAll[i] = b;
    bool inz = (i >= 2048 && i < 3072);
    r0All[i] = inz ? zw0[i - 2048] : 0.f;
    r1All[i] = inz ? zw0[1024 + (i - 2048)] : 0.f;
    if (i < 3072)
      biasL2[i] = (i < 1024) ? yb1[i] : (i < 2048) ? db1[i - 1024] : zb1[i - 2048];
    return;
  }
  {  // bucket bookkeeping: single block, 256 threads x 64 items
    __shared__ int h[8], sseg[8];
    const int tid = threadIdx.x;
    if (tid < 8) h[tid] = 0;
    __syncthreads();
    const int base = tid * 64;
    int lc[7] = {0, 0, 0, 0, 0, 0, 0};
    for (int i = 0; i < 64; ++i) lc[t[base + i]]++;
    int myoff[7];
#pragma unroll
    for (int k = 0; k < 7; ++k) myoff[k] = atomicAdd(&h[k], lc[k]);
    __syncthreads();
    if (tid == 0) {
      int s = 0;
      for (int k = 0; k < 7; ++k) { sseg[k] = s; s += h[k]; }
      sseg[7] = s;
    }
    __syncthreads();
    if (tid < 7) { cnt[tid] = h[tid]; seg[tid] = sseg[tid]; }
    if (tid == 7) seg[7] = sseg[7];
    int cur[7];
#pragma unroll
    for (int k = 0; k < 7; ++k) cur[k] = sseg[k] + myoff[k];
    for (int i = 0; i < 64; ++i) {
      int b = base + i, k = t[b];
      int r = cur[k]++;
      rank[b] = r;
      sids[r] = b;
    }
  }
}

// ---------------------------------------------------------------------------
// fused layer-1: [16384,1024] x [1024,3328] -> {a1y,a1d,a1z,ht1}
// XCD-swizzled 1D grid; BK=32 swizzled k-loop.
__global__ __launch_bounds__(256) void gemm_l1_k(
    const bf16* __restrict__ A, const bf16* __restrict__ Bt,
    const float* __restrict__ biasAll, const float* __restrict__ r0All,
    const float* __restrict__ r1All, const float* __restrict__ yv,
    const float* __restrict__ dv, bf16* __restrict__ a1y,
    bf16* __restrict__ a1d, bf16* __restrict__ a1z, bf16* __restrict__ ht1) {
  __shared__ bf16 As[128 * 32];
  __shared__ bf16 Bs[128 * 32];
  const int tid = threadIdx.x, lane = tid & 63, wid = tid >> 6;
  const int wm = wid >> 1, wn = wid & 1, quad = lane >> 4, l15 = lane & 15;
  const int id = blockIdx.x;
  const int xcd = id & 7, lid = id >> 3;               // lid in [0,416)
  const int pass = lid / 208, rem = lid - pass * 208;  // 208 = 8m x 26n
  const int mt = xcd * 16 + pass * 8 + (rem & 7), nt = rem >> 3;
  const int bm0 = mt * 128, bn0 = nt * 128;
  const int sr = tid >> 2, scol = swz_scol(tid);
  const bf16* gA[2];
  const bf16* gB[2];
#pragma unroll
  for (int c = 0; c < 2; ++c) {
    gA[c] = A + (size_t)(bm0 + c * 64 + sr) * 1024 + scol;
    gB[c] = Bt + (size_t)(bn0 + c * 64 + sr) * 1024 + scol;
  }
  const bf16* aBase = &As[(wm * 64 + l15) * 32];
  const bf16* bBase = &Bs[(wn * 64 + l15) * 32];
  const int colsel = swz_colsel(quad, l15);
  f32x4 acc[4][4] = {};
  kloop32<2, 2, 4>(gA, gB, As, Bs, tid, aBase, bBase, colsel, acc, 32);

  const int g = nt >> 3;
  bf16* dst = (g == 0) ? a1y : (g == 1) ? a1d : (g == 2) ? a1z : ht1;
  const int ldc = (g == 3) ? 256 : 1024;
  const int colb = bn0 - g * 1024;
  float bv[4], z0[4], z1[4];
#pragma unroll
  for (int c = 0; c < 4; ++c) {
    int gn = bn0 + wn * 64 + c * 16 + l15;
    bv[c] = biasAll[gn]; z0[c] = r0All[gn]; z1[c] = r1All[gn];
  }
#pragma unroll
  for (int r = 0; r < 4; ++r) {
#pragma unroll
    for (int q = 0; q < 4; ++q) {
      int gm = bm0 + wm * 64 + r * 16 + quad * 4 + q;
      float yy = yv[gm], dd = dv[gm];
#pragma unroll
      for (int c = 0; c < 4; ++c) {
        float v = acc[r][c][q] + bv[c] + yy * z0[c] + dd * z1[c];
        dst[(size_t)gm * ldc + colb + wn * 64 + c * 16 + l15] = __float2bfloat16(eluf(v));
      }
    }
  }
}

// fused layer-2 + t-layer-2: blocks [0,3072) = y1|d1|z1 (K=1024, XCD-swizzled),
// blocks [3072,3328) = t1 (K=256). hz rows written permuted via rank[].
__global__ __launch_bounds__(256) void gemm_l2t_k(
    const bf16* __restrict__ a1y, const bf16* __restrict__ a1d,
    const bf16* __restrict__ a1z, const bf16* __restrict__ ht1,
    const bf16* __restrict__ BtL2, const bf16* __restrict__ tw1t,
    const float* __restrict__ biasL2, const float* __restrict__ tb1,
    bf16* __restrict__ hyd, bf16* __restrict__ hzg, bf16* __restrict__ ht2,
    const int* __restrict__ rank) {
  __shared__ bf16 As[128 * 32];
  __shared__ bf16 Bs[128 * 32];
  const int tid = threadIdx.x, lane = tid & 63, wid = tid >> 6;
  const int wm = wid >> 1, wn = wid & 1, quad = lane >> 4, l15 = lane & 15;
  const int id = blockIdx.x;
  int bm0, bn0, Ka, g;
  const bf16 *Aptr, *Bptr;
  if (id < 3072) {
    const int xcd = id & 7, lid = id >> 3;               // lid in [0,384)
    const int pass = lid / 192, rem = lid - pass * 192;  // 192 = 8m x 24n
    const int mt = xcd * 16 + pass * 8 + (rem & 7), nt = rem >> 3;
    bm0 = mt * 128; bn0 = nt * 128; Ka = 1024;
    g = nt >> 3;
    Aptr = (g == 0) ? a1y : (g == 1) ? a1d : a1z;
    Bptr = BtL2;
  } else {
    const int local = id - 3072;
    bm0 = (local >> 1) * 128; bn0 = (local & 1) * 128; Ka = 256;
    g = 3; Aptr = ht1; Bptr = tw1t;
  }
  const int sr = tid >> 2, scol = swz_scol(tid);
  const bf16* gA[2];
  const bf16* gB[2];
#pragma unroll
  for (int c = 0; c < 2; ++c) {
    gA[c] = Aptr + (size_t)(bm0 + c * 64 + sr) * Ka + scol;
    gB[c] = Bptr + (size_t)(bn0 + c * 64 + sr) * Ka + scol;
  }
  const bf16* aBase = &As[(wm * 64 + l15) * 32];
  const bf16* bBase = &Bs[(wn * 64 + l15) * 32];
  const int colsel = swz_colsel(quad, l15);
  f32x4 acc[4][4] = {};
  kloop32<2, 2, 4>(gA, gB, As, Bs, tid, aBase, bBase, colsel, acc, Ka >> 5);

  const float* bias = (g == 3) ? tb1 : biasL2;
  float bv[4];
#pragma unroll
  for (int c = 0; c < 4; ++c) bv[c] = bias[bn0 + wn * 64 + c * 16 + l15];
#pragma unroll
  for (int r = 0; r < 4; ++r) {
#pragma unroll
    for (int q = 0; q < 4; ++q) {
      int gm = bm0 + wm * 64 + r * 16 + quad * 4 + q;
      bf16* dst; size_t rowoff;
      if (g == 2) { dst = hzg; rowoff = (size_t)rank[gm] * 1024 + (size_t)(bn0 - 2048); }
      else if (g == 3) { dst = ht2; rowoff = (size_t)gm * 256 + bn0; }
      else { dst = hyd; rowoff = (size_t)gm * 2048 + bn0; }
#pragma unroll
      for (int c = 0; c < 4; ++c) {
        float v = acc[r][c][q] + bv[c];
        dst[rowoff + wn * 64 + c * 16 + l15] = __float2bfloat16(eluf(v));
      }
    }
  }
}

// ---------------------------------------------------------------------------
// merged tail: z-head bucketed GEMM (blocks < ZB) + y/d heads + t-logits.
// zhead: per-bucket [cnt x 1024] x [1024 x 512], 128x64 tiles, BK=32 swizzle.
#define ZMT 28  // max m-tiles per bucket (covers 3584 rows; mean 2341, +27 sigma)
#define ZB (7 * ZMT * 8)
__global__ __launch_bounds__(256) void tail_k(
    const bf16* __restrict__ hzg, const bf16* __restrict__ zhWt,
    const float* __restrict__ zhb, const int* __restrict__ seg,
    const int* __restrict__ cnts, const int* __restrict__ sids,
    const bf16* __restrict__ hyd, const bf16* __restrict__ ht2,
    const int* __restrict__ t, const float* __restrict__ yhW,
    const float* __restrict__ yhb, const float* __restrict__ dhW,
    const float* __restrict__ dhb, const float* __restrict__ tw2,
    const float* __restrict__ tb2, float* __restrict__ out) {
  __shared__ bf16 As[128 * 32];  // 8 KB
  __shared__ bf16 Bs[64 * 32];   // 4 KB
  const int tid = threadIdx.x, lane = tid & 63, wid = tid >> 6;
  const int wv = wid, quad = lane >> 4, l15 = lane & 15;
  if (blockIdx.x < ZB) {
    const int kb = blockIdx.x / (ZMT * 8);
    const int r = blockIdx.x % (ZMT * 8);
    const int cnt = cnts[kb];
    const int bm0 = (r >> 3) * 128;
    if (bm0 >= cnt) return;
    const int n0 = (r & 7) * 64;
    const int wm = wid >> 1, wn = wid & 1;
    const int base = seg[kb];
    const int sr = tid >> 2, scol = swz_scol(tid);
    const bf16* gA[2];
    const bf16* gB[1];
#pragma unroll
    for (int c = 0; c < 2; ++c) {
      int rr = bm0 + c * 64 + sr;
      if (rr >= cnt) rr = cnt - 1;
      gA[c] = hzg + (size_t)(base + rr) * 1024 + scol;
    }
    gB[0] = zhWt + (size_t)kb * 512 * 1024 + (size_t)(n0 + sr) * 1024 + scol;
    const bf16* aBase = &As[(wm * 64 + l15) * 32];
    const bf16* bBase = &Bs[(wn * 32 + l15) * 32];
    const int colsel = swz_colsel(quad, l15);
    f32x4 acc[4][2] = {};
    kloop32<2, 1, 2>(gA, gB, As, Bs, tid, aBase, bBase, colsel, acc, 32);
    const float* bias = zhb + (size_t)kb * 512;
    float bv[2]; int gnn[2];
#pragma unroll
    for (int c = 0; c < 2; ++c) {
      gnn[c] = n0 + wn * 32 + c * 16 + l15;
      bv[c] = bias[gnn[c]];
    }
#pragma unroll
    for (int r2 = 0; r2 < 4; ++r2)
#pragma unroll
      for (int q = 0; q < 4; ++q) {
        int lm = bm0 + wm * 64 + r2 * 16 + quad * 4 + q;
        if (lm < cnt) {
          int gm = sids[base + lm];
          size_t ob = (size_t)gm * 523 + 11;
#pragma unroll
          for (int c = 0; c < 2; ++c) {
            float v = acc[r2][c][q] + bv[c];
            int n = gnn[c];
            out[ob + n] = (n < 256) ? fminf(fmaxf(v, -100.f), 100.f)
                                    : fminf(softplusf(v) + 0.001f, 100.f);
          }
        }
      }
    return;
  }
  const int hid = blockIdx.x - ZB;
  if (hid < 4096) {  // y/d heads
    const int b = hid * 4 + wv;
    const int tb = t[b];
    const float* yW = yhW + (size_t)tb * 2048;
    const float* dW = dhW + (size_t)tb * 2048;
    float s0 = 0.f, s1 = 0.f, s2 = 0.f, s3 = 0.f;
    for (int i = lane; i < 1024; i += 64) {
      float a = __bfloat162float(hyd[(size_t)b * 2048 + i]);
      float c = __bfloat162float(hyd[(size_t)b * 2048 + 1024 + i]);
      s0 += a * yW[2 * i]; s1 += a * yW[2 * i + 1];
      s2 += c * dW[2 * i]; s3 += c * dW[2 * i + 1];
    }
#pragma unroll
    for (int off = 32; off > 0; off >>= 1) {
      s0 += __shfl_down(s0, off); s1 += __shfl_down(s1, off);
      s2 += __shfl_down(s2, off); s3 += __shfl_down(s3, off);
    }
    if (lane == 0) {
      size_t o = (size_t)b * 523;
      out[o + 7] = fminf(fmaxf(s0 + yhb[tb * 2], -1e6f), 1e6f);
      out[o + 8] = fminf(softplusf(s1 + yhb[tb * 2 + 1]) + 1e-3f, 1e6f);
      out[o + 9] = fminf(fmaxf(s2 + dhb[tb * 2], -1e6f), 1e6f);
      out[o + 10] = fminf(softplusf(s3 + dhb[tb * 2 + 1]) + 1e-3f, 1e6f);
    }
  } else {  // t logits
    const int b = (hid - 4096) * 4 + wv;
    float h[4];
#pragma unroll
    for (int j = 0; j < 4; ++j)
      h[j] = __bfloat162float(ht2[(size_t)b * 256 + lane * 4 + j]);
    float pp[7];
#pragma unroll
    for (int kk = 0; kk < 7; ++kk) {
      float s = 0.f;
#pragma unroll
      for (int j = 0; j < 4; ++j) s += h[j] * tw2[(lane * 4 + j) * 7 + kk];
      pp[kk] = s;
    }
#pragma unroll
    for (int kk = 0; kk < 7; ++kk)
#pragma unroll
      for (int off = 32; off > 0; off >>= 1) pp[kk] += __shfl_down(pp[kk], off);
    if (lane == 0) {
#pragma unroll
      for (int kk = 0; kk < 7; ++kk) {
        float v = eluf(pp[kk] + tb2[kk]);
        out[(size_t)b * 523 + kk] = fminf(fmaxf(v, -10.f), 10.f);
      }
    }
  }
}

// ---------------------------------------------------------------------------
extern "C" void kernel_launch(void* const* d_in, const int* in_sizes, int n_in,
                              void* d_out, int out_size, void* d_ws, size_t ws_size,
                              hipStream_t stream) {
  const float* x   = (const float*)d_in[0];
  const int*   t   = (const int*)d_in[1];
  const float* yv  = (const float*)d_in[2];
  const float* dv  = (const float*)d_in[3];
  const float* tw0 = (const float*)d_in[4];
  const float* tb0 = (const float*)d_in[5];
  const float* tw1 = (const float*)d_in[6];
  const float* tb1 = (const float*)d_in[7];
  const float* tw2 = (const float*)d_in[8];
  const float* tb2 = (const float*)d_in[9];
  const float* yw0 = (const float*)d_in[10];
  const float* yb0 = (const float*)d_in[11];
  const float* yw1 = (const float*)d_in[12];
  const float* yb1 = (const float*)d_in[13];
  const float* yhW = (const float*)d_in[14];
  const float* yhb = (const float*)d_in[15];
  const float* dw0 = (const float*)d_in[16];
  const float* db0 = (const float*)d_in[17];
  const float* dw1 = (const float*)d_in[18];
  const float* db1 = (const float*)d_in[19];
  const float* dhW = (const float*)d_in[20];
  const float* dhb = (const float*)d_in[21];
  const float* zw0 = (const float*)d_in[22];
  const float* zb0 = (const float*)d_in[23];
  const float* zw1 = (const float*)d_in[24];
  const float* zb1 = (const float*)d_in[25];
  const float* zhW = (const float*)d_in[26];
  const float* zhb = (const float*)d_in[27];
  float* out = (float*)d_out;

  const int B = 16384;
  char* p = (char*)d_ws;
  auto take = [&](size_t bytes) {
    char* r = p;
    p += (bytes + 255) & ~(size_t)255;
    return r;
  };
  bf16*  BtL1    = (bf16*)take((size_t)3328 * 1024 * 2);
  bf16*  BtL2    = (bf16*)take((size_t)3072 * 1024 * 2);
  bf16*  tw1t    = (bf16*)take((size_t)256 * 256 * 2);
  bf16*  zhWt    = (bf16*)take((size_t)7 * 512 * 1024 * 2);
  float* biasAll = (float*)take(3328 * 4);
  float* r0All   = (float*)take(3328 * 4);
  float* r1All   = (float*)take(3328 * 4);
  float* biasL2  = (float*)take(3072 * 4);
  int*   cnt     = (int*)take(8 * 4);
  int*   seg     = (int*)take(8 * 4);
  int*   rank    = (int*)take((size_t)B * 4);
  int*   sids    = (int*)take((size_t)B * 4);
  bf16*  xb      = (bf16*)take((size_t)B * 1024 * 2);  // reused as hzg after L1
  bf16*  a1y     = (bf16*)take((size_t)B * 1024 * 2);
  bf16*  a1d     = (bf16*)take((size_t)B * 1024 * 2);
  bf16*  a1z     = (bf16*)take((size_t)B * 1024 * 2);
  bf16*  ht1     = (bf16*)take((size_t)B * 256 * 2);
  bf16*  hyd     = (bf16*)take((size_t)B * 2048 * 2);
  bf16*  ht2     = (bf16*)take((size_t)B * 256 * 2);
  bf16*  hzg     = xb;

  prep_all_k<<<19022, 256, 0, stream>>>(x, xb, yw0, dw0, zw0, tw0, BtL1,
                                        yw1, dw1, zw1, BtL2, tw1, tw1t, zhW, zhWt,
                                        yb0, db0, zb0, tb0, yb1, db1, zb1,
                                        biasAll, r0All, r1All, biasL2,
                                        t, cnt, seg, rank, sids);
  gemm_l1_k<<<3328, 256, 0, stream>>>(xb, BtL1, biasAll, r0All, r1All,
                                      yv, dv, a1y, a1d, a1z, ht1);
  gemm_l2t_k<<<3328, 256, 0, stream>>>(a1y, a1d, a1z, ht1, BtL2, tw1t,
                                       biasL2, tb1, hyd, hzg, ht2, rank);
  tail_k<<<ZB + 8192, 256, 0, stream>>>(hzg, zhWt, zhb, seg, cnt, sids,
                                        hyd, ht2, t, yhW, yhb, dhW, dhb,
                                        tw2, tb2, out);
}